// Round 2
// baseline (38.023 us; speedup 1.0000x reference)
//
#include <hip/hip_runtime.h>
#include <math.h>

// B=2, N=512, DIM=3, C_IN=64, C_OUT=64
// ws layout (floats): s[1024] | gm4[2*512*256] | an[2*512*512] | part[4*1024*192]
#define WS_S    0
#define WS_GM4  1024
#define WS_AN   (1024 + 262144)
#define WS_PART (1024 + 262144 + 524288)

typedef const __attribute__((address_space(1))) void g_void;
typedef __attribute__((address_space(3))) void l_void;

// ---------------------------------------------------------------------------
// Kernel A: per (b,j):  s[bj] = sum_c ||geom[bj,:,c]|| * norm_w[c] + norm_b
//                       gm4[bj][co][0..2] = sum_c geom[bj,d,c] * theta[c,co]
// ---------------------------------------------------------------------------
__global__ __launch_bounds__(64) void precompute_kernel(
    const float* __restrict__ geom,    // [1024,3,64]
    const float* __restrict__ theta,   // [65,64]
    const float* __restrict__ norm_w,  // [65]
    const float* __restrict__ norm_b,  // [1]
    float* __restrict__ s,             // [1024]
    float* __restrict__ gm4)           // [1024,64,4]
{
    const int bj  = blockIdx.x;
    const int tid = threadIdx.x;       // = c, and = co
    __shared__ float g[192];           // [d*64 + c]

    const float* gb = geom + (size_t)bj * 192;
    g[tid]       = gb[tid];
    g[tid + 64]  = gb[tid + 64];
    g[tid + 128] = gb[tid + 128];
    __syncthreads();

    {
        float g0 = g[tid], g1 = g[64 + tid], g2 = g[128 + tid];
        float t = sqrtf(g0 * g0 + g1 * g1 + g2 * g2) * norm_w[tid];
        for (int off = 32; off > 0; off >>= 1) t += __shfl_down(t, off);
        if (tid == 0) s[bj] = t + norm_b[0];
    }

    float a0 = 0.f, a1 = 0.f, a2 = 0.f;
    for (int c = 0; c < 64; ++c) {
        float th = theta[c * 64 + tid];
        a0 = fmaf(g[c],       th, a0);
        a1 = fmaf(g[64 + c],  th, a1);
        a2 = fmaf(g[128 + c], th, a2);
    }
    float4 v = make_float4(a0, a1, a2, 0.f);
    *reinterpret_cast<float4*>(gm4 + (size_t)bj * 256 + tid * 4) = v;
}

// ---------------------------------------------------------------------------
// Kernel A2: an[b,i,j] = adj * (s[b,j] + nw64*||rel[b,i,j,:]|| + emb[b,i,j])
// ---------------------------------------------------------------------------
__global__ __launch_bounds__(256) void naf_kernel(
    const float* __restrict__ adj,     // [1024,512]
    const float* __restrict__ rel,     // [1024,512,3]
    const float* __restrict__ emb,     // [1024,512]
    const float* __restrict__ norm_w,  // [65]
    const float* __restrict__ s,       // [1024]
    float* __restrict__ an)            // [1024,512]
{
    const int bi  = blockIdx.x;        // b*512 + i
    const int b   = bi >> 9;
    const float nw64 = norm_w[64];
    #pragma unroll
    for (int k = 0; k < 2; ++k) {
        int j = threadIdx.x + k * 256;
        size_t p = (size_t)bi * 512 + j;
        float r0 = rel[p * 3], r1 = rel[p * 3 + 1], r2 = rel[p * 3 + 2];
        float naf = s[b * 512 + j] + nw64 * sqrtf(r0 * r0 + r1 * r1 + r2 * r2)
                  + emb[p];
        an[p] = adj[p] * naf;
    }
}

// ---------------------------------------------------------------------------
// Main: block = (b, i-tile of 4, j-quarter of 128). 4 waves, wave = one i,
// lane = co. Gm tile double-buffered in LDS via global_load_lds; per-(i,j)
// operands via wave-uniform (scalar) loads.
//   part[jq][b*512+i][d*64+co] = sum_{j in q} w * (gm + r_d*t64)
//   w = relu(al*an + be*adj)
// ---------------------------------------------------------------------------
__global__ __launch_bounds__(256) void main_kernel(
    const float* __restrict__ adj,     // [1024,512]
    const float* __restrict__ rel,     // [1024,512,3]
    const float* __restrict__ an,      // [1024,512]
    const float* __restrict__ theta,   // [65,64]
    const float* __restrict__ alpha,   // [64]
    const float* __restrict__ beta,    // [64]
    const float* __restrict__ gm4,     // [1024,64,4]
    float* __restrict__ part)          // [4][1024][192]
{
    const int bx   = blockIdx.x;       // 1024
    const int jq   = bx & 3;
    const int itg  = bx >> 2;          // 0..255
    const int b    = itg >> 7;
    const int i0   = (itg & 127) * 4;
    const int tid  = threadIdx.x;
    const int lane = tid & 63;
    const int wv   = tid >> 6;
    const int bi   = __builtin_amdgcn_readfirstlane(b * 512 + i0 + wv);
    const int j0   = jq * 128;

    __shared__ float buf[2][4096];     // 2 x 16KB : 16 j x 64 co x 4

    const float al  = alpha[lane];
    const float be  = beta[lane];
    const float t64 = theta[64 * 64 + lane];

    const float* gmb  = gm4 + ((size_t)b * 512 + j0) * 256;
    const float* anr  = an  + (size_t)bi * 512 + j0;
    const float* adjr = adj + (size_t)bi * 512 + j0;
    const float* relr = rel + ((size_t)bi * 512 + j0) * 3;

    // stage chunk 0 (16 j = 16KB): 16 units of 1KB; wave wv takes units wv+4u
    #pragma unroll
    for (int u = 0; u < 4; ++u) {
        int unit = u * 4 + wv;
        __builtin_amdgcn_global_load_lds(
            (g_void*)(gmb + unit * 256 + lane * 4),
            (l_void*)(&buf[0][unit * 256]), 16, 0, 0);
    }

    float acc0 = 0.f, acc1 = 0.f, acc2 = 0.f;
    for (int c = 0; c < 8; ++c) {
        __syncthreads();               // drains vmcnt -> chunk c staged
        if (c < 7) {
            const float* src = gmb + (c + 1) * 4096;
            #pragma unroll
            for (int u = 0; u < 4; ++u) {
                int unit = u * 4 + wv;
                __builtin_amdgcn_global_load_lds(
                    (g_void*)(src + unit * 256 + lane * 4),
                    (l_void*)(&buf[(c + 1) & 1][unit * 256]), 16, 0, 0);
            }
        }
        const float* bp = buf[c & 1];
        const int jb = c * 16;
        #pragma unroll 4
        for (int jj = 0; jj < 16; ++jj) {
            int j = jb + jj;
            float s_an  = anr[j];                    // wave-uniform -> s_load
            float s_adj = adjr[j];
            float r0 = relr[j * 3], r1 = relr[j * 3 + 1], r2 = relr[j * 3 + 2];
            float w = fmaxf(fmaf(al, s_an, be * s_adj), 0.f);
            float4 g = *reinterpret_cast<const float4*>(bp + (jj << 8) + lane * 4);
            float t0 = fmaf(r0, t64, g.x);
            float t1 = fmaf(r1, t64, g.y);
            float t2 = fmaf(r2, t64, g.z);
            acc0 = fmaf(w, t0, acc0);
            acc1 = fmaf(w, t1, acc1);
            acc2 = fmaf(w, t2, acc2);
        }
    }

    float* pw = part + ((size_t)jq * 1024 + bi) * 192 + lane;
    pw[0]   = acc0;
    pw[64]  = acc1;
    pw[128] = acc2;
}

// ---------------------------------------------------------------------------
// Reduce: out[k] = sum_{jq<4} part[jq][k],  k < 1024*192
// ---------------------------------------------------------------------------
__global__ __launch_bounds__(256) void reduce_kernel(
    const float* __restrict__ part, float* __restrict__ out)
{
    int idx = blockIdx.x * 256 + threadIdx.x;      // 768*256 = 196608 exact
    out[idx] = part[idx] + part[196608 + idx] + part[2 * 196608 + idx]
             + part[3 * 196608 + idx];
}

extern "C" void kernel_launch(void* const* d_in, const int* in_sizes, int n_in,
                              void* d_out, int out_size, void* d_ws, size_t ws_size,
                              hipStream_t stream) {
    const float* geom   = (const float*)d_in[0];
    const float* adj    = (const float*)d_in[1];
    const float* rel    = (const float*)d_in[2];
    const float* emb    = (const float*)d_in[3];
    const float* theta  = (const float*)d_in[4];
    const float* norm_w = (const float*)d_in[5];
    const float* norm_b = (const float*)d_in[6];
    const float* alpha  = (const float*)d_in[7];
    const float* beta   = (const float*)d_in[8];
    float* out = (float*)d_out;

    float* ws   = (float*)d_ws;
    float* s    = ws + WS_S;
    float* gm4  = ws + WS_GM4;
    float* an   = ws + WS_AN;
    float* part = ws + WS_PART;

    precompute_kernel<<<1024, 64, 0, stream>>>(geom, theta, norm_w, norm_b, s, gm4);
    naf_kernel<<<1024, 256, 0, stream>>>(adj, rel, emb, norm_w, s, an);
    main_kernel<<<1024, 256, 0, stream>>>(adj, rel, an, theta, alpha, beta, gm4, part);
    reduce_kernel<<<768, 256, 0, stream>>>(part, out);
}

// Round 3
// 35.446 us; speedup vs baseline: 1.0727x; 1.0727x over previous
//
#include <hip/hip_runtime.h>
#include <math.h>

// B=2, N=512, DIM=3, C_IN=64, C_OUT=64
// ws layout (floats): s[1024] | gm4[1024*256] | pk2[1024*512*2]
#define WS_S   0
#define WS_GM4 1024
#define WS_PK2 (1024 + 262144)

// ---------------------------------------------------------------------------
// Kernel A: per (b,j):  s[bj] = sum_c ||geom[bj,:,c]|| * norm_w[c] + norm_b
//                       gm4[bj][co] = {sum_c geom[bj,d,c]*theta[c,co]}_{d=0..2}
// ---------------------------------------------------------------------------
__global__ __launch_bounds__(64) void precompute_kernel(
    const float* __restrict__ geom,    // [1024,3,64]
    const float* __restrict__ theta,   // [65,64]
    const float* __restrict__ norm_w,  // [65]
    const float* __restrict__ norm_b,  // [1]
    float* __restrict__ s,             // [1024]
    float* __restrict__ gm4)           // [1024,64,4]
{
    const int bj  = blockIdx.x;
    const int tid = threadIdx.x;       // = c, and = co
    __shared__ float g[192];           // [d*64 + c]

    const float* gb = geom + (size_t)bj * 192;
    g[tid]       = gb[tid];
    g[tid + 64]  = gb[tid + 64];
    g[tid + 128] = gb[tid + 128];
    __syncthreads();

    {
        float g0 = g[tid], g1 = g[64 + tid], g2 = g[128 + tid];
        float t = sqrtf(g0 * g0 + g1 * g1 + g2 * g2) * norm_w[tid];
        for (int off = 32; off > 0; off >>= 1) t += __shfl_down(t, off);
        if (tid == 0) s[bj] = t + norm_b[0];
    }

    float a0 = 0.f, a1 = 0.f, a2 = 0.f;
    for (int c = 0; c < 64; ++c) {
        float th = theta[c * 64 + tid];
        a0 = fmaf(g[c],       th, a0);
        a1 = fmaf(g[64 + c],  th, a1);
        a2 = fmaf(g[128 + c], th, a2);
    }
    *reinterpret_cast<float4*>(gm4 + (size_t)bj * 256 + tid * 4) =
        make_float4(a0, a1, a2, 0.f);
}

// ---------------------------------------------------------------------------
// Kernel A2: pk2[b,i,j] = { adj*naf, adj }  (naf = s[b,j]+nw64*||rel||+emb)
// ---------------------------------------------------------------------------
__global__ __launch_bounds__(256) void naf_kernel(
    const float* __restrict__ adj,     // [1024,512]
    const float* __restrict__ rel,     // [1024,512,3]
    const float* __restrict__ emb,     // [1024,512]
    const float* __restrict__ norm_w,  // [65]
    const float* __restrict__ s,       // [1024]
    float* __restrict__ pk2)           // [1024,512,2]
{
    const int bi = blockIdx.x;         // b*512 + i
    const int b  = bi >> 9;
    const float nw64 = norm_w[64];
    #pragma unroll
    for (int k = 0; k < 2; ++k) {
        int j = threadIdx.x + k * 256;
        size_t p = (size_t)bi * 512 + j;
        float r0 = rel[p * 3], r1 = rel[p * 3 + 1], r2 = rel[p * 3 + 2];
        float naf = s[b * 512 + j] + nw64 * sqrtf(r0 * r0 + r1 * r1 + r2 * r2)
                  + emb[p];
        float a = adj[p];
        *reinterpret_cast<float2*>(pk2 + p * 2) = make_float2(a * naf, a);
    }
}

// ---------------------------------------------------------------------------
// Main: grid 512 = (b, i-quad, j-half). 4 waves = j-quarters of the half
// (64 j each); each wave keeps 4 i's in registers (Gm reuse x4). lane = co.
// Per-(i,j) scalars via wave-uniform loads (scalar pipe); Gm via one
// dwordx4 L2 load per (wave,j). In-block LDS reduce over the 4 waves, then
// atomicAdd combines the two jh blocks into zero-initialized out.
//   w = relu(al*an + be*adj);  out += w * (gm_d + rel_d * t64)
// ---------------------------------------------------------------------------
__global__ __launch_bounds__(256) void main_kernel(
    const float* __restrict__ rel,     // [1024,512,3]
    const float* __restrict__ pk2,     // [1024,512,2]
    const float* __restrict__ theta,   // [65,64]
    const float* __restrict__ alpha,   // [64]
    const float* __restrict__ beta,    // [64]
    const float* __restrict__ gm4,     // [1024,64,4]
    float* __restrict__ out)           // [1024,192]
{
    const int bx   = blockIdx.x;       // ((b*128 + iq)*2 + jh)
    const int jh   = bx & 1;
    const int iq   = (bx >> 1) & 127;
    const int b    = bx >> 8;
    const int tid  = threadIdx.x;
    const int lane = tid & 63;         // co
    const int wv   = __builtin_amdgcn_readfirstlane(tid >> 6);
    const int j0   = jh * 256 + wv * 64;
    const int bi0  = b * 512 + iq * 4;

    const float al  = alpha[lane];
    const float be  = beta[lane];
    const float t64 = theta[64 * 64 + lane];

    const float* gmb = gm4 + ((size_t)(b * 512 + j0)) * 256 + lane * 4;

    float acc[4][3];
    #pragma unroll
    for (int il = 0; il < 4; ++il)
        acc[il][0] = acc[il][1] = acc[il][2] = 0.f;

    #pragma unroll 4
    for (int jj = 0; jj < 64; ++jj) {
        float4 g = *reinterpret_cast<const float4*>(gmb + jj * 256);
        #pragma unroll
        for (int il = 0; il < 4; ++il) {
            size_t p = (size_t)(bi0 + il) * 512 + (j0 + jj);  // wave-uniform
            float an   = pk2[p * 2];
            float adjv = pk2[p * 2 + 1];
            float r0 = rel[p * 3], r1 = rel[p * 3 + 1], r2 = rel[p * 3 + 2];
            float w = fmaxf(fmaf(al, an, be * adjv), 0.f);
            acc[il][0] = fmaf(w, fmaf(r0, t64, g.x), acc[il][0]);
            acc[il][1] = fmaf(w, fmaf(r1, t64, g.y), acc[il][1]);
            acc[il][2] = fmaf(w, fmaf(r2, t64, g.z), acc[il][2]);
        }
    }

    __shared__ float red[4][768];
    #pragma unroll
    for (int il = 0; il < 4; ++il) {
        red[wv][il * 192 + lane]       = acc[il][0];
        red[wv][il * 192 + 64 + lane]  = acc[il][1];
        red[wv][il * 192 + 128 + lane] = acc[il][2];
    }
    __syncthreads();

    for (int k = tid; k < 768; k += 256) {
        float v = red[0][k] + red[1][k] + red[2][k] + red[3][k];
        int il = k / 192, r = k - il * 192;
        atomicAdd(&out[(size_t)(bi0 + il) * 192 + r], v);
    }
}

extern "C" void kernel_launch(void* const* d_in, const int* in_sizes, int n_in,
                              void* d_out, int out_size, void* d_ws, size_t ws_size,
                              hipStream_t stream) {
    const float* geom   = (const float*)d_in[0];
    const float* adj    = (const float*)d_in[1];
    const float* rel    = (const float*)d_in[2];
    const float* emb    = (const float*)d_in[3];
    const float* theta  = (const float*)d_in[4];
    const float* norm_w = (const float*)d_in[5];
    const float* norm_b = (const float*)d_in[6];
    const float* alpha  = (const float*)d_in[7];
    const float* beta   = (const float*)d_in[8];
    float* out = (float*)d_out;

    float* ws  = (float*)d_ws;
    float* s   = ws + WS_S;
    float* gm4 = ws + WS_GM4;
    float* pk2 = ws + WS_PK2;

    hipMemsetAsync(out, 0, (size_t)out_size * sizeof(float), stream);
    precompute_kernel<<<1024, 64, 0, stream>>>(geom, theta, norm_w, norm_b, s, gm4);
    naf_kernel<<<1024, 256, 0, stream>>>(adj, rel, emb, norm_w, s, pk2);
    main_kernel<<<512, 256, 0, stream>>>(rel, pk2, theta, alpha, beta, gm4, out);
}

// Round 4
// 31.409 us; speedup vs baseline: 1.2106x; 1.1285x over previous
//
#include <hip/hip_runtime.h>
#include <math.h>

// B=2, N=512, DIM=3, C_IN=64, C_OUT=64
// ws layout (floats): s[1024] | gm4[1024*256] | pk[1024*512*4 (uint4)]
#define WS_S   0
#define WS_GM4 1024
#define WS_PK  (1024 + 262144)

static __device__ __forceinline__ unsigned bf16b(float x) {
    unsigned u = __builtin_bit_cast(unsigned, x);
    return (u + 0x7FFFu + ((u >> 16) & 1u)) >> 16;   // RNE truncate to bf16
}
static __device__ __forceinline__ float bflo(unsigned bits) {  // low bf16
    return __builtin_bit_cast(float, bits << 16);
}
static __device__ __forceinline__ float bfhi(unsigned bits) {  // high bf16
    return __builtin_bit_cast(float, bits & 0xFFFF0000u);
}

// ---------------------------------------------------------------------------
// Fused prep, grid 1280 x 256:
//  blocks [0,256):   4 bj each: s[bj] = sum_c ||geom[bj,:,c]||*norm_w[c]+norm_b
//                    gm4[bj][co] = {geom[bj,:,:] @ theta[:64,co]}  (float4)
//  blocks [256,1280): bi = bx-256: pk[bi][j] = {ae, adj, bf16(r0,r1), bf16(r2)}
//                    ae = adj*(nw64*||rel||+emb)   (NO s dependence!)
//  blocks [0,1024):  also zero out[bx*192 .. +192)
// ---------------------------------------------------------------------------
__global__ __launch_bounds__(256) void prep_kernel(
    const float* __restrict__ geom,    // [1024,3,64]
    const float* __restrict__ adj,     // [1024,512]
    const float* __restrict__ rel,     // [1024,512,3]
    const float* __restrict__ emb,     // [1024,512]
    const float* __restrict__ theta,   // [65,64]
    const float* __restrict__ norm_w,  // [65]
    const float* __restrict__ norm_b,  // [1]
    float* __restrict__ s,             // [1024]
    float* __restrict__ gm4,           // [1024,64,4]
    uint4* __restrict__ pk,            // [1024,512]
    float* __restrict__ out)           // [1024,192] (zeroed here)
{
    const int bx  = blockIdx.x;
    const int tid = threadIdx.x;

    if (bx < 1024 && tid < 192) out[(size_t)bx * 192 + tid] = 0.f;

    if (bx < 256) {
        const int sub  = tid >> 6;      // which of 4 bj
        const int lane = tid & 63;      // = c, and = co
        const int bj   = bx * 4 + sub;
        __shared__ float g[4][192];     // [d*64 + c]
        const float* gb = geom + (size_t)bj * 192;
        g[sub][lane]       = gb[lane];
        g[sub][lane + 64]  = gb[lane + 64];
        g[sub][lane + 128] = gb[lane + 128];
        __syncthreads();

        {
            float g0 = g[sub][lane], g1 = g[sub][64 + lane], g2 = g[sub][128 + lane];
            float t = sqrtf(g0 * g0 + g1 * g1 + g2 * g2) * norm_w[lane];
            for (int off = 32; off > 0; off >>= 1) t += __shfl_down(t, off);
            if (lane == 0) s[bj] = t + norm_b[0];
        }

        float a0 = 0.f, a1 = 0.f, a2 = 0.f;
        for (int c = 0; c < 64; ++c) {
            float th = theta[c * 64 + lane];
            a0 = fmaf(g[sub][c],       th, a0);
            a1 = fmaf(g[sub][64 + c],  th, a1);
            a2 = fmaf(g[sub][128 + c], th, a2);
        }
        *reinterpret_cast<float4*>(gm4 + (size_t)bj * 256 + lane * 4) =
            make_float4(a0, a1, a2, 0.f);
    } else {
        const int bi = bx - 256;
        const float nw64 = norm_w[64];
        #pragma unroll
        for (int k = 0; k < 2; ++k) {
            int j = tid + k * 256;
            size_t p = (size_t)bi * 512 + j;
            float r0 = rel[p * 3], r1 = rel[p * 3 + 1], r2 = rel[p * 3 + 2];
            float e2 = fmaf(nw64, sqrtf(r0 * r0 + r1 * r1 + r2 * r2), emb[p]);
            float a  = adj[p];
            uint4 q;
            q.x = __builtin_bit_cast(unsigned, a * e2);
            q.y = __builtin_bit_cast(unsigned, a);
            q.z = bf16b(r0) | (bf16b(r1) << 16);
            q.w = bf16b(r2) << 16;
            pk[p] = q;
        }
    }
}

// ---------------------------------------------------------------------------
// Main, grid 512 = ((b*128+iq)*2+jh), 256 thr. Wave = j-quarter of the half
// (64 j), 4 i's in registers; lane = co.
//   an = fmaf(adj, s_j, ae);  w = relu(al*an + be*adj)
//   acc_d += w * (gm_d + r_d*t64)
// Gm: one dwordx4/lane per (wave,j), reused for 4 i. Per-pair operands: ONE
// 16-B broadcast load. Block LDS-reduces its 4 waves; 2 jh-blocks combine
// via atomicAdd into prep-zeroed out (2-way fp add is order-exact).
// ---------------------------------------------------------------------------
__global__ __launch_bounds__(256) void main_kernel(
    const uint4* __restrict__ pk,      // [1024,512]
    const float* __restrict__ s,       // [1024]
    const float* __restrict__ gm4,     // [1024,64,4]
    const float* __restrict__ theta,   // [65,64]
    const float* __restrict__ alpha,   // [64]
    const float* __restrict__ beta,    // [64]
    float* __restrict__ out)           // [1024,192]
{
    const int bx   = blockIdx.x;
    const int jh   = bx & 1;
    const int iq   = (bx >> 1) & 127;
    const int b    = bx >> 8;
    const int tid  = threadIdx.x;
    const int lane = tid & 63;         // co
    const int wv   = __builtin_amdgcn_readfirstlane(tid >> 6);
    const int bi0  = b * 512 + iq * 4;
    const int j0   = jh * 256 + wv * 64;

    __shared__ float s_l[256];
    __shared__ float red[4][768];
    s_l[tid] = s[b * 512 + jh * 256 + tid];
    __syncthreads();

    const float al  = alpha[lane];
    const float be  = beta[lane];
    const float t64 = theta[64 * 64 + lane];

    const float* gmb = gm4 + ((size_t)(b * 512 + j0)) * 256 + lane * 4;
    const uint4* pk0 = pk + (size_t)bi0 * 512 + j0;

    float acc[4][3];
    #pragma unroll
    for (int il = 0; il < 4; ++il)
        acc[il][0] = acc[il][1] = acc[il][2] = 0.f;

    #pragma unroll 4
    for (int jj = 0; jj < 64; ++jj) {
        float4 g  = *reinterpret_cast<const float4*>(gmb + (size_t)jj * 256);
        float  sj = s_l[wv * 64 + jj];
        #pragma unroll
        for (int il = 0; il < 4; ++il) {
            uint4 q = pk0[(size_t)il * 512 + jj];   // 16-B broadcast
            float ae = __builtin_bit_cast(float, q.x);
            float av = __builtin_bit_cast(float, q.y);
            float r0 = bflo(q.z);
            float r1 = bfhi(q.z);
            float r2 = bfhi(q.w);
            float an = fmaf(av, sj, ae);
            float w  = fmaxf(fmaf(al, an, be * av), 0.f);
            acc[il][0] = fmaf(w, fmaf(r0, t64, g.x), acc[il][0]);
            acc[il][1] = fmaf(w, fmaf(r1, t64, g.y), acc[il][1]);
            acc[il][2] = fmaf(w, fmaf(r2, t64, g.z), acc[il][2]);
        }
    }

    #pragma unroll
    for (int il = 0; il < 4; ++il) {
        red[wv][il * 192 + lane]       = acc[il][0];
        red[wv][il * 192 + 64 + lane]  = acc[il][1];
        red[wv][il * 192 + 128 + lane] = acc[il][2];
    }
    __syncthreads();

    #pragma unroll
    for (int k = tid; k < 768; k += 256) {
        float v = red[0][k] + red[1][k] + red[2][k] + red[3][k];
        int il = k / 192, r = k - il * 192;
        atomicAdd(&out[(size_t)(bi0 + il) * 192 + r], v);
    }
}

extern "C" void kernel_launch(void* const* d_in, const int* in_sizes, int n_in,
                              void* d_out, int out_size, void* d_ws, size_t ws_size,
                              hipStream_t stream) {
    const float* geom   = (const float*)d_in[0];
    const float* adj    = (const float*)d_in[1];
    const float* rel    = (const float*)d_in[2];
    const float* emb    = (const float*)d_in[3];
    const float* theta  = (const float*)d_in[4];
    const float* norm_w = (const float*)d_in[5];
    const float* norm_b = (const float*)d_in[6];
    const float* alpha  = (const float*)d_in[7];
    const float* beta   = (const float*)d_in[8];
    float* out = (float*)d_out;

    float* ws  = (float*)d_ws;
    float* s   = ws + WS_S;
    float* gm4 = ws + WS_GM4;
    uint4* pk  = (uint4*)(ws + WS_PK);

    prep_kernel<<<1280, 256, 0, stream>>>(geom, adj, rel, emb, theta, norm_w,
                                          norm_b, s, gm4, pk, out);
    main_kernel<<<512, 256, 0, stream>>>(pk, s, gm4, theta, alpha, beta, out);
}

// Round 5
// 25.415 us; speedup vs baseline: 1.4961x; 1.2359x over previous
//
#include <hip/hip_runtime.h>
#include <math.h>

// B=2, N=512, DIM=3, C_IN=64, C_OUT=64
// ws layout (floats): s[1024] | gm4[1024*256]
#define WS_S   0
#define WS_GM4 1024

static __device__ __forceinline__ unsigned bf16b(float x) {
    unsigned u = __builtin_bit_cast(unsigned, x);
    return (u + 0x7FFFu + ((u >> 16) & 1u)) >> 16;   // RNE to bf16
}

// ---------------------------------------------------------------------------
// P1, grid 256 x 256: 4 bj per block.
//   s[bj]      = sum_c ||geom[bj,:,c]|| * norm_w[c] + norm_b
//   gm4[bj][co] = { geom[bj,:,:] @ theta[:64,co] , 0 }   (float4)
// ---------------------------------------------------------------------------
__global__ __launch_bounds__(256) void p1_kernel(
    const float* __restrict__ geom,    // [1024,3,64]
    const float* __restrict__ theta,   // [65,64]
    const float* __restrict__ norm_w,  // [65]
    const float* __restrict__ norm_b,  // [1]
    float* __restrict__ s,             // [1024]
    float* __restrict__ gm4)           // [1024,64,4]
{
    const int bx   = blockIdx.x;
    const int sub  = threadIdx.x >> 6;  // which of 4 bj
    const int lane = threadIdx.x & 63;  // = c, and = co
    const int bj   = bx * 4 + sub;
    __shared__ float g[4][192];         // [d*64 + c]

    const float* gb = geom + (size_t)bj * 192;
    g[sub][lane]       = gb[lane];
    g[sub][lane + 64]  = gb[lane + 64];
    g[sub][lane + 128] = gb[lane + 128];
    __syncthreads();

    {
        float g0 = g[sub][lane], g1 = g[sub][64 + lane], g2 = g[sub][128 + lane];
        float t = sqrtf(g0 * g0 + g1 * g1 + g2 * g2) * norm_w[lane];
        for (int off = 32; off > 0; off >>= 1) t += __shfl_down(t, off);
        if (lane == 0) s[bj] = t + norm_b[0];
    }

    float a0 = 0.f, a1 = 0.f, a2 = 0.f;
    for (int c = 0; c < 64; ++c) {
        float th = theta[c * 64 + lane];
        a0 = fmaf(g[sub][c],       th, a0);
        a1 = fmaf(g[sub][64 + c],  th, a1);
        a2 = fmaf(g[sub][128 + c], th, a2);
    }
    *reinterpret_cast<float4*>(gm4 + (size_t)bj * 256 + lane * 4) =
        make_float4(a0, a1, a2, 0.f);
}

// ---------------------------------------------------------------------------
// Main, grid 512 x 512thr. Block = (b, i-pair); 8 waves, wave = 64-j chunk
// covering both i's (gm reg-reuse x2). lane = co.
// Setup packs per-(i,j) operands into LDS uint4 {an, adj, bf16 r0r1, bf16 r2}
// (an = adj*naf, s folded). Inner loop: 1 broadcast ds_read_b128 per pair +
// 1 shared dwordx4 gm load per j + 11 VALU. Block-reduce over waves, direct
// store. No atomics.
// ---------------------------------------------------------------------------
__global__ __launch_bounds__(512, 4) void main_kernel(
    const float* __restrict__ adj,     // [1024,512]
    const float* __restrict__ rel,     // [1024,512,3]
    const float* __restrict__ emb,     // [1024,512]
    const float* __restrict__ s,       // [1024]
    const float* __restrict__ gm4,     // [1024,64,4]
    const float* __restrict__ theta,   // [65,64]
    const float* __restrict__ norm_w,  // [65]
    const float* __restrict__ alpha,   // [64]
    const float* __restrict__ beta,    // [64]
    float* __restrict__ out)           // [1024,192]
{
    const int bx   = blockIdx.x;       // b*256 + ip
    const int b    = bx >> 8;
    const int ip   = bx & 255;
    const int bi0  = b * 512 + ip * 2;
    const int tid  = threadIdx.x;      // 0..511
    const int lane = tid & 63;         // co
    const int wv   = tid >> 6;         // 0..7 -> j chunk

    __shared__ uint4 pk_l[512][2];     // 16 KB, [j][i]

    // ---- setup: pack operands for j = tid, both i ----
    {
        const int j = tid;
        const float sj   = s[b * 512 + j];
        const float nw64 = norm_w[64];
        #pragma unroll
        for (int i = 0; i < 2; ++i) {
            size_t p = (size_t)(bi0 + i) * 512 + j;
            const float* rp = rel + p * 3;
            float r0 = rp[0], r1 = rp[1], r2 = rp[2];
            float a   = adj[p];
            float naf = sj + nw64 * sqrtf(r0 * r0 + r1 * r1 + r2 * r2) + emb[p];
            uint4 q;
            q.x = __builtin_bit_cast(unsigned, a * naf);
            q.y = __builtin_bit_cast(unsigned, a);
            q.z = bf16b(r0) | (bf16b(r1) << 16);
            q.w = bf16b(r2) << 16;
            pk_l[j][i] = q;
        }
    }
    __syncthreads();

    const float al  = alpha[lane];
    const float be  = beta[lane];
    const float t64 = theta[64 * 64 + lane];

    const float* gmb = gm4 + ((size_t)(b * 512 + wv * 64)) * 256 + lane * 4;

    float acc[2][3];
    acc[0][0] = acc[0][1] = acc[0][2] = 0.f;
    acc[1][0] = acc[1][1] = acc[1][2] = 0.f;

    #pragma unroll 4
    for (int jj = 0; jj < 64; ++jj) {
        float4 g = *reinterpret_cast<const float4*>(gmb + (size_t)jj * 256);
        #pragma unroll
        for (int i = 0; i < 2; ++i) {
            uint4 q = pk_l[wv * 64 + jj][i];         // broadcast b128
            float an = __builtin_bit_cast(float, q.x);
            float av = __builtin_bit_cast(float, q.y);
            float r0 = __builtin_bit_cast(float, q.z << 16);
            float r1 = __builtin_bit_cast(float, q.z & 0xFFFF0000u);
            float r2 = __builtin_bit_cast(float, q.w);
            float w  = fmaxf(fmaf(al, an, be * av), 0.f);
            acc[i][0] = fmaf(w, fmaf(r0, t64, g.x), acc[i][0]);
            acc[i][1] = fmaf(w, fmaf(r1, t64, g.y), acc[i][1]);
            acc[i][2] = fmaf(w, fmaf(r2, t64, g.z), acc[i][2]);
        }
    }

    __syncthreads();                    // done with pk_l; reuse as reduce buf
    float* red = (float*)pk_l;          // [8][384]
    #pragma unroll
    for (int i = 0; i < 2; ++i) {
        red[wv * 384 + i * 192 + lane]       = acc[i][0];
        red[wv * 384 + i * 192 + 64 + lane]  = acc[i][1];
        red[wv * 384 + i * 192 + 128 + lane] = acc[i][2];
    }
    __syncthreads();

    if (tid < 384) {
        float v = 0.f;
        #pragma unroll
        for (int w8 = 0; w8 < 8; ++w8) v += red[w8 * 384 + tid];
        int i = tid / 192;
        int r = tid - i * 192;
        out[(size_t)(bi0 + i) * 192 + r] = v;
    }
}

extern "C" void kernel_launch(void* const* d_in, const int* in_sizes, int n_in,
                              void* d_out, int out_size, void* d_ws, size_t ws_size,
                              hipStream_t stream) {
    const float* geom   = (const float*)d_in[0];
    const float* adj    = (const float*)d_in[1];
    const float* rel    = (const float*)d_in[2];
    const float* emb    = (const float*)d_in[3];
    const float* theta  = (const float*)d_in[4];
    const float* norm_w = (const float*)d_in[5];
    const float* norm_b = (const float*)d_in[6];
    const float* alpha  = (const float*)d_in[7];
    const float* beta   = (const float*)d_in[8];
    float* out = (float*)d_out;

    float* ws  = (float*)d_ws;
    float* s   = ws + WS_S;
    float* gm4 = ws + WS_GM4;

    p1_kernel<<<256, 256, 0, stream>>>(geom, theta, norm_w, norm_b, s, gm4);
    main_kernel<<<512, 512, 0, stream>>>(adj, rel, emb, s, gm4, theta, norm_w,
                                         alpha, beta, out);
}

// Round 9
// 22.567 us; speedup vs baseline: 1.6849x; 1.1262x over previous
//
#include <hip/hip_runtime.h>
#include <math.h>

// B=2, N=512, DIM=3, C_IN=64, C_OUT=64
// ws layout (floats): s[1024] | gm4[1024*256]
#define WS_S   0
#define WS_GM4 1024

typedef unsigned int u32;

static __device__ __forceinline__ u32 bf16b(float x) {
    u32 u = __builtin_bit_cast(u32, x);
    return (u + 0x7FFFu + ((u >> 16) & 1u)) >> 16;   // RNE to bf16
}

// ---------------------------------------------------------------------------
// Prep, grid 512 x 256:
//  all bx:  zero out[bx*384 .. +384)
//  bx<256:  4 bj each:  s[bj] = sum_c ||geom[bj,:,c]||*norm_w[c] + norm_b
//           gm4[bj][co] = {geom[bj,:,:] @ theta[:64,co], 0}   (float4)
// ---------------------------------------------------------------------------
__global__ __launch_bounds__(256) void prep_kernel(
    const float* __restrict__ geom,    // [1024,3,64]
    const float* __restrict__ theta,   // [65,64]
    const float* __restrict__ norm_w,  // [65]
    const float* __restrict__ norm_b,  // [1]
    float* __restrict__ s,             // [1024]
    float* __restrict__ gm4,           // [1024,64,4]
    float* __restrict__ out)           // [1024,192]
{
    const int bx  = blockIdx.x;
    const int tid = threadIdx.x;

    for (int k = tid; k < 384; k += 256)
        out[(size_t)bx * 384 + k] = 0.f;

    if (bx < 256) {
        const int sub  = tid >> 6;      // which of 4 bj
        const int lane = tid & 63;      // = c, and = co
        const int bj   = bx * 4 + sub;
        __shared__ float g[4][192];     // [d*64 + c]
        const float* gb = geom + (size_t)bj * 192;
        g[sub][lane]       = gb[lane];
        g[sub][lane + 64]  = gb[lane + 64];
        g[sub][lane + 128] = gb[lane + 128];
        __syncthreads();

        {
            float g0 = g[sub][lane], g1 = g[sub][64 + lane], g2 = g[sub][128 + lane];
            float t = sqrtf(g0 * g0 + g1 * g1 + g2 * g2) * norm_w[lane];
            for (int off = 32; off > 0; off >>= 1) t += __shfl_down(t, off);
            if (lane == 0) s[bj] = t + norm_b[0];
        }

        float a0 = 0.f, a1 = 0.f, a2 = 0.f;
        for (int c = 0; c < 64; ++c) {
            float th = theta[c * 64 + lane];
            a0 = fmaf(g[sub][c],       th, a0);
            a1 = fmaf(g[sub][64 + c],  th, a1);
            a2 = fmaf(g[sub][128 + c], th, a2);
        }
        *reinterpret_cast<float4*>(gm4 + (size_t)bj * 256 + lane * 4) =
            make_float4(a0, a1, a2, 0.f);
    }
}

// ---------------------------------------------------------------------------
// Main, grid 512 = (b*256 + iq*2 + jh), 512 thr = 8 waves (16 waves/CU).
// Block = (b, i-quad, j-half). Wave = 32-j chunk x 4 i; lane = co.
// Setup packs per-(i,j) operands into LDS pk_l[il][j] (i-MAJOR: setup
// ds_write_b128 is lane-contiguous -> conflict-free; R5's [j][i] layout was
// a structural 4-8 way write conflict). Inner loop: 1 broadcast
// ds_read_b128/pair + 1 coalesced dwordx4 gm/j reused x4 + 9 VALU/pair.
// 8-wave LDS reduce, two jh halves combine via atomicAdd into prep-zeroed
// out (2 commutative addends -> deterministic).
//   an = a*naf (s folded in pack);  w = relu(al*an + be*a)
//   acc_d += w * (gm_d + r_d*t64)
// ---------------------------------------------------------------------------
__global__ __launch_bounds__(512) void main_kernel(
    const float* __restrict__ adj,     // [1024,512]
    const float* __restrict__ rel,     // [1024,512,3]
    const float* __restrict__ emb,     // [1024,512]
    const float* __restrict__ s,       // [1024]
    const float* __restrict__ gm4,     // [1024,64,4]
    const float* __restrict__ theta,   // [65,64]
    const float* __restrict__ norm_w,  // [65]
    const float* __restrict__ alpha,   // [64]
    const float* __restrict__ beta,    // [64]
    float* __restrict__ out)           // [1024,192]
{
    const int bx   = blockIdx.x;
    const int jh   = bx & 1;
    const int iq   = (bx >> 1) & 127;
    const int b    = bx >> 8;
    const int tid  = threadIdx.x;      // 0..511
    const int lane = tid & 63;         // co
    const int wv   = tid >> 6;         // 0..7
    const int bi0  = b * 512 + iq * 4;
    const int j0   = jh * 256;

    __shared__ uint4 pk_l[4][256];     // 16 KB, i-MAJOR
    __shared__ float red[8][768];      // 24 KB

    // ---- setup: pack operands; t = il*256 + j, lane-contiguous writes ----
    {
        const float nw64 = norm_w[64];
        #pragma unroll
        for (int u = 0; u < 2; ++u) {
            int t  = tid + u * 512;        // 0..1023
            int il = t >> 8;               // 0..3
            int j  = t & 255;
            size_t p = (size_t)(bi0 + il) * 512 + j0 + j;
            const float* rp = rel + p * 3;
            float r0 = rp[0], r1 = rp[1], r2 = rp[2];
            float a   = adj[p];
            float naf = s[b * 512 + j0 + j]
                      + nw64 * sqrtf(r0 * r0 + r1 * r1 + r2 * r2) + emb[p];
            uint4 q;
            q.x = __builtin_bit_cast(u32, a * naf);
            q.y = __builtin_bit_cast(u32, a);
            q.z = bf16b(r0) | (bf16b(r1) << 16);
            q.w = bf16b(r2) << 16;
            pk_l[il][j] = q;
        }
    }
    __syncthreads();

    const float al  = alpha[lane];
    const float be  = beta[lane];
    const float t64 = theta[64 * 64 + lane];

    const float4* gmv =
        (const float4*)gm4 + ((size_t)(b * 512 + j0 + wv * 32)) * 64 + lane;

    float acc[4][3];
    #pragma unroll
    for (int il = 0; il < 4; ++il)
        acc[il][0] = acc[il][1] = acc[il][2] = 0.f;

    #pragma unroll 4
    for (int jj = 0; jj < 32; ++jj) {
        float4 g = gmv[(size_t)jj * 64];
        #pragma unroll
        for (int il = 0; il < 4; ++il) {
            uint4 q = pk_l[il][wv * 32 + jj];        // broadcast b128 (free)
            float an = __builtin_bit_cast(float, q.x);
            float av = __builtin_bit_cast(float, q.y);
            float r0 = __builtin_bit_cast(float, q.z << 16);
            float r1 = __builtin_bit_cast(float, q.z & 0xFFFF0000u);
            float r2 = __builtin_bit_cast(float, q.w);
            float w  = fmaxf(fmaf(al, an, be * av), 0.f);
            acc[il][0] = fmaf(w, fmaf(r0, t64, g.x), acc[il][0]);
            acc[il][1] = fmaf(w, fmaf(r1, t64, g.y), acc[il][1]);
            acc[il][2] = fmaf(w, fmaf(r2, t64, g.z), acc[il][2]);
        }
    }

    // ---- 8-wave reduce (lane-contiguous b32, conflict-free) ----
    float* rw = &red[wv][lane];
    #pragma unroll
    for (int il = 0; il < 4; ++il) {
        rw[il * 192]       = acc[il][0];
        rw[il * 192 + 64]  = acc[il][1];
        rw[il * 192 + 128] = acc[il][2];
    }
    __syncthreads();

    for (int k = tid; k < 768; k += 512) {
        float v = 0.f;
        #pragma unroll
        for (int w8 = 0; w8 < 8; ++w8) v += red[w8][k];
        int il = k / 192, r = k - il * 192;
        atomicAdd(&out[(size_t)(bi0 + il) * 192 + r], v);
    }
}

extern "C" void kernel_launch(void* const* d_in, const int* in_sizes, int n_in,
                              void* d_out, int out_size, void* d_ws, size_t ws_size,
                              hipStream_t stream) {
    const float* geom   = (const float*)d_in[0];
    const float* adj    = (const float*)d_in[1];
    const float* rel    = (const float*)d_in[2];
    const float* emb    = (const float*)d_in[3];
    const float* theta  = (const float*)d_in[4];
    const float* norm_w = (const float*)d_in[5];
    const float* norm_b = (const float*)d_in[6];
    const float* alpha  = (const float*)d_in[7];
    const float* beta   = (const float*)d_in[8];
    float* out = (float*)d_out;

    float* ws  = (float*)d_ws;
    float* s   = ws + WS_S;
    float* gm4 = ws + WS_GM4;

    prep_kernel<<<512, 256, 0, stream>>>(geom, theta, norm_w, norm_b, s, gm4, out);
    main_kernel<<<512, 512, 0, stream>>>(adj, rel, emb, s, gm4, theta, norm_w,
                                         alpha, beta, out);
}